// Round 5
// baseline (138.893 us; speedup 1.0000x reference)
//
#include <hip/hip_runtime.h>
#include <math.h>

// Problem constants (fixed by setup_inputs)
#define N_TOTAL 2097152
#define NT 256              // threads per block
#define NC 8                // elements per thread
#define EPB (NT * NC)       // 2048 elements per block
#define NB (N_TOTAL / EPB)  // 1024 blocks -> 4 blocks/CU on 256 CUs
#define NWAVES (NT / 64)    // 4 waves per block

// Projective map on homogeneous (x, g, 1):
//   x' = (al*x + be) / (ga*x + de);  g' = (e*x + c*g + f) / (ga*x + de)
// Matrix [[al,0,be],[e,c,f],[ga,0,de]] — closed under composition.
// COMPOSITION in fp64 (near-parabolic composites, det ~ 1/T^2, T up to 2e7:
// fp32 cancellation catastrophic — proven rounds 1-2). Element math fp32.
struct DMat { double al, be, ga, de, c, e, f; };

__device__ __forceinline__ DMat dmat_identity() {
    DMat m; m.al = 1.0; m.be = 0.0; m.ga = 0.0; m.de = 1.0; m.c = 1.0; m.e = 0.0; m.f = 0.0;
    return m;
}

// A applied AFTER B (matrix product A*B)
__device__ __forceinline__ DMat dmat_compose(const DMat& A, const DMat& B) {
    DMat r;
    r.al = A.al * B.al + A.be * B.ga;
    r.be = A.al * B.be + A.be * B.de;
    r.ga = A.ga * B.al + A.de * B.ga;
    r.de = A.ga * B.be + A.de * B.de;
    r.c  = A.c * B.c;
    r.e  = A.e * B.al + A.c * B.e + A.f * B.ga;
    r.f  = A.e * B.be + A.c * B.f + A.f * B.de;
    return r;
}

__device__ __forceinline__ void dmat_normalize(DMat& m) {
    double mx = fmax(fabs(m.al), fabs(m.be));
    mx = fmax(mx, fabs(m.ga));
    mx = fmax(mx, fabs(m.de));
    mx = fmax(mx, fabs(m.c));
    mx = fmax(mx, fabs(m.e));
    mx = fmax(mx, fabs(m.f));
    if (!(mx > 0.0) || isinf(mx)) return;
    double inv = 1.0 / mx;
    m.al *= inv; m.be *= inv; m.ga *= inv; m.de *= inv;
    m.c *= inv; m.e *= inv; m.f *= inv;
}

__device__ __forceinline__ DMat dmat_shfl_up(const DMat& m, int d) {
    DMat r;
    r.al = __shfl_up(m.al, d, 64);
    r.be = __shfl_up(m.be, d, 64);
    r.ga = __shfl_up(m.ga, d, 64);
    r.de = __shfl_up(m.de, d, 64);
    r.c  = __shfl_up(m.c,  d, 64);
    r.e  = __shfl_up(m.e,  d, 64);
    r.f  = __shfl_up(m.f,  d, 64);
    return r;
}

// Ordered inclusive Kogge-Stone scan within one wave (barrier-free).
// At exit lane L holds M_L * M_{L-1} * ... * M_0.
__device__ __forceinline__ DMat dmat_wave_scan(DMat mine, int lane) {
    #pragma unroll
    for (int d = 1; d < 64; d <<= 1) {
        DMat o = dmat_shfl_up(mine, d);   // all lanes execute the shuffle
        if (lane >= d) {
            mine = dmat_compose(mine, o); // earlier goes on the right
            dmat_normalize(mine);
        }
    }
    return mine;
}

// Element matrix from fp32 values. a = dg + s2u2, U = sigma2*u, V = u.
// Algebra: a-UV = dg, a-2UV = dg-s2u2 (removes cancellation and ops).
__device__ __forceinline__ DMat elem_mat_f32(float P, float dg, float s2u2,
                                             float sigma2, float u, float yy) {
    float p = P * P;
    float U = sigma2 * u;
    DMat m;
    m.al = (double)(p * (dg - s2u2));
    m.be = (double)(u * u);
    m.ga = -(double)(p * U * U);
    m.de = (double)(dg + s2u2);
    m.c  = (double)(P * dg);
    m.e  = -(double)(yy * p * U);
    m.f  = (double)(yy * u);
    return m;
}

__device__ __forceinline__ void dmat_store_g(double* p, const DMat& m) {
    p[0] = m.al; p[1] = m.be; p[2] = m.ga; p[3] = m.de;
    p[4] = m.c;  p[5] = m.e;  p[6] = m.f;
}

__device__ __forceinline__ DMat dmat_load_g(const double* p) {
    DMat m = {p[0], p[1], p[2], p[3], p[4], p[5], p[6]};
    return m;
}

// -------- Kernel 1: block composite + per-wave in-block exclusives --------
__global__ __launch_bounds__(NT, 4) void k_upsweep(
    const float* __restrict__ t, const int* __restrict__ band,
    const float* __restrict__ y, const float* __restrict__ yerr,
    const float* __restrict__ lad, const float* __restrict__ lkp,
    double* __restrict__ block_comp, double* __restrict__ wave_excl)
{
    __shared__ double smw[7 * NWAVES];
    const int tid = threadIdx.x;
    const int lane = tid & 63;
    const int wv = tid >> 6;
    const float sigma2 = __expf(2.f * lkp[0]);
    const float inv_ell = __expf(-lkp[1]);
    float amps[4] = {1.f, __expf(lad[0]), __expf(lad[1]), __expf(lad[2])};

    const int base = (blockIdx.x * NT + tid) * NC;
    float tprev = (base == 0) ? 0.f : t[base - 1];
    DMat acc = dmat_identity();
    #pragma unroll
    for (int k = 0; k < NC; k += 4) {
        float4 tv = *reinterpret_cast<const float4*>(t + base + k);
        float4 yv = *reinterpret_cast<const float4*>(y + base + k);
        float4 ev = *reinterpret_cast<const float4*>(yerr + base + k);
        int4   bv = *reinterpret_cast<const int4*>(band + base + k);
        float tc[4] = {tv.x, tv.y, tv.z, tv.w};
        float yc[4] = {yv.x, yv.y, yv.z, yv.w};
        float ec[4] = {ev.x, ev.y, ev.z, ev.w};
        int   bc[4] = {bv.x, bv.y, bv.z, bv.w};
        #pragma unroll
        for (int j = 0; j < 4; ++j) {
            float u = amps[bc[j] & 3];
            float dg = ec[j] * ec[j];
            float s2u2 = sigma2 * u * u;
            float P = ((base + k + j) == 0) ? 0.f
                    : __expf(-(tc[j] - tprev) * inv_ell);
            // 8-compose fp64 chain: entries bounded (<~1e18), normalize once
            acc = dmat_compose(elem_mat_f32(P, dg, s2u2, sigma2, u, yc[j]), acc);
            tprev = tc[j];
        }
    }
    dmat_normalize(acc);
    DMat incl = dmat_wave_scan(acc, lane);
    if (lane == 63) {
        #define STW(idx, val) smw[(idx) * NWAVES + wv] = (val)
        STW(0, incl.al); STW(1, incl.be); STW(2, incl.ga); STW(3, incl.de);
        STW(4, incl.c);  STW(5, incl.e);  STW(6, incl.f);
        #undef STW
    }
    __syncthreads();
    if (tid == 0) {
        DMat pre = dmat_identity();
        for (int w = 0; w < NWAVES; ++w) {
            dmat_store_g(wave_excl + (blockIdx.x * NWAVES + w) * 7, pre);
            DMat Ww = {smw[0 * NWAVES + w], smw[1 * NWAVES + w],
                       smw[2 * NWAVES + w], smw[3 * NWAVES + w],
                       smw[4 * NWAVES + w], smw[5 * NWAVES + w],
                       smw[6 * NWAVES + w]};
            pre = dmat_compose(Ww, pre);
            dmat_normalize(pre);
        }
        dmat_store_g(block_comp + blockIdx.x * 7, pre);
    }
}

// ----- Kernel 2: spine scan -> per-block exclusive; zero accum/counter ----
__global__ __launch_bounds__(NT) void k_spine(
    const double* __restrict__ block_comp, double* __restrict__ block_excl,
    double* __restrict__ accum, unsigned int* __restrict__ counter)
{
    __shared__ double smw[7 * NWAVES];
    const int tid = threadIdx.x;
    const int lane = tid & 63;
    const int wv = tid >> 6;
    if (tid == 0) {
        accum[0] = 0.0;
        accum[1] = 0.0;
        *counter = 0u;
    }
    // each thread owns 4 consecutive block composites (NB == 4*NT)
    DMat m[4];
    #pragma unroll
    for (int i = 0; i < 4; ++i)
        m[i] = dmat_load_g(block_comp + (4 * tid + i) * 7);
    DMat acc = m[0];
    #pragma unroll
    for (int i = 1; i < 4; ++i) acc = dmat_compose(m[i], acc);
    dmat_normalize(acc);
    DMat incl = dmat_wave_scan(acc, lane);
    if (lane == 63) {
        #define STW(idx, val) smw[(idx) * NWAVES + wv] = (val)
        STW(0, incl.al); STW(1, incl.be); STW(2, incl.ga); STW(3, incl.de);
        STW(4, incl.c);  STW(5, incl.e);  STW(6, incl.f);
        #undef STW
    }
    __syncthreads();
    DMat wpre = dmat_identity();
    for (int w = 0; w < wv; ++w) {   // wave-uniform loop, <= 3 composes
        DMat Ww = {smw[0 * NWAVES + w], smw[1 * NWAVES + w],
                   smw[2 * NWAVES + w], smw[3 * NWAVES + w],
                   smw[4 * NWAVES + w], smw[5 * NWAVES + w],
                   smw[6 * NWAVES + w]};
        wpre = dmat_compose(Ww, wpre);
    }
    dmat_normalize(wpre);
    DMat lex = dmat_shfl_up(incl, 1);
    if (lane == 0) lex = dmat_identity();
    DMat tex = dmat_compose(lex, wpre);  // exclusive over blocks [0, 4*tid)
    dmat_normalize(tex);
    #pragma unroll
    for (int i = 0; i < 4; ++i) {
        dmat_store_g(block_excl + (4 * tid + i) * 7, tex);
        tex = dmat_compose(m[i], tex);
        dmat_normalize(tex);
    }
}

// -------- Kernel 3: replay (fp32 recurrence) + fused finalize -------------
__global__ __launch_bounds__(NT, 4) void k_replay(
    const float* __restrict__ t, const int* __restrict__ band,
    const float* __restrict__ y, const float* __restrict__ yerr,
    const float* __restrict__ lad, const float* __restrict__ lkp,
    const double* __restrict__ block_excl, const double* __restrict__ wave_excl,
    double* __restrict__ accum, unsigned int* __restrict__ counter,
    float* __restrict__ out)
{
    __shared__ double smr[2 * NWAVES];
    const int tid = threadIdx.x;
    const int lane = tid & 63;
    const int wv = tid >> 6;
    const float sigma2 = __expf(2.f * lkp[0]);
    const float inv_ell = __expf(-lkp[1]);
    float amps[4] = {1.f, __expf(lad[0]), __expf(lad[1]), __expf(lad[2])};

    const int base = (blockIdx.x * NT + tid) * NC;
    float tprev = (base == 0) ? 0.f : t[base - 1];

    float Pv[NC], dgv[NC], uv[NC], yv_[NC];
    DMat acc = dmat_identity();
    #pragma unroll
    for (int k = 0; k < NC; k += 4) {
        float4 tv = *reinterpret_cast<const float4*>(t + base + k);
        float4 yv = *reinterpret_cast<const float4*>(y + base + k);
        float4 ev = *reinterpret_cast<const float4*>(yerr + base + k);
        int4   bv = *reinterpret_cast<const int4*>(band + base + k);
        float tc[4] = {tv.x, tv.y, tv.z, tv.w};
        float yc[4] = {yv.x, yv.y, yv.z, yv.w};
        float ec[4] = {ev.x, ev.y, ev.z, ev.w};
        int   bc[4] = {bv.x, bv.y, bv.z, bv.w};
        #pragma unroll
        for (int j = 0; j < 4; ++j) {
            float u = amps[bc[j] & 3];
            float dg = ec[j] * ec[j];
            float s2u2 = sigma2 * u * u;
            float P = ((base + k + j) == 0) ? 0.f
                    : __expf(-(tc[j] - tprev) * inv_ell);
            Pv[k + j] = P; dgv[k + j] = dg; uv[k + j] = u; yv_[k + j] = yc[j];
            acc = dmat_compose(elem_mat_f32(P, dg, s2u2, sigma2, u, yc[j]), acc);
            tprev = tc[j];
        }
    }
    dmat_normalize(acc);
    DMat incl = dmat_wave_scan(acc, lane);
    DMat lex = dmat_shfl_up(incl, 1);
    if (lane == 0) lex = dmat_identity();

    // global exclusive = lane_excl(in wave) * wave_excl(in block) * block_excl
    DMat Ew = dmat_load_g(wave_excl + (blockIdx.x * NWAVES + wv) * 7);
    DMat Eb = dmat_load_g(block_excl + blockIdx.x * 7);
    DMat Fw = dmat_compose(Ew, Eb);
    dmat_normalize(Fw);
    DMat F = dmat_compose(lex, Fw);
    // apply at (x,g)=(0,0): always well-conditioned (0 far from repelling pt)
    float x = 0.f, g = 0.f;
    if (F.de != 0.0) {
        double invde = 1.0 / F.de;
        x = (float)(F.be * invde);
        g = (float)(F.f  * invde);
    }
    if (!isfinite(x)) x = 0.f;
    if (!isfinite(g)) g = 0.f;

    // fp32 celerite recurrence — the reference's arithmetic
    float s_logD = 0.f, s_quad = 0.f;
    #pragma unroll
    for (int k = 0; k < NC; ++k) {
        float P = Pv[k], dg = dgv[k], u = uv[k], yy = yv_[k];
        float U = sigma2 * u;
        float a = dg + U * u;
        float p = P * P;
        float S = p * x;
        float D = a - U * U * S;
        if (!(D > 1e-30f)) D = 1e-30f;  // NaN-proof; no-op when math is right
        float W = (u - S * U) / D;
        float gn = P * g;
        float z = yy - U * gn;
        s_logD += __logf(D);
        s_quad += z * z / D;
        x = S + D * W * W;
        g = gn + W * z;
    }

    // wave shuffle reduce (commutative), then LDS combine of 4 waves
    double sl = (double)s_logD, sq = (double)s_quad;
    #pragma unroll
    for (int d = 32; d > 0; d >>= 1) {
        sl += __shfl_down(sl, d, 64);
        sq += __shfl_down(sq, d, 64);
    }
    if (lane == 0) { smr[wv] = sl; smr[NWAVES + wv] = sq; }
    __syncthreads();
    if (tid == 0) {
        double tl = smr[0] + smr[1] + smr[2] + smr[3];
        double tq = smr[NWAVES] + smr[NWAVES + 1] + smr[NWAVES + 2] + smr[NWAVES + 3];
        atomicAdd(&accum[0], tl);
        atomicAdd(&accum[1], tq);
        __threadfence();
        unsigned int old = atomicAdd(counter, 1u);
        if (old == NB - 1) {   // last block: finalize
            double s0 = atomicAdd(&accum[0], 0.0);
            double s1 = atomicAdd(&accum[1], 0.0);
            double r = -0.5 * (s0 + s1
                       + (double)N_TOTAL * 1.8378770664093454836);  // log(2*pi)
            out[0] = (float)r;
        }
    }
}

extern "C" void kernel_launch(void* const* d_in, const int* in_sizes, int n_in,
                              void* d_out, int out_size, void* d_ws, size_t ws_size,
                              hipStream_t stream)
{
    const float* t    = (const float*)d_in[0];
    const int*   band = (const int*)d_in[1];
    const float* y    = (const float*)d_in[2];
    const float* yerr = (const float*)d_in[3];
    const float* lad  = (const float*)d_in[4];
    const float* lkp  = (const float*)d_in[5];

    double* dws        = (double*)d_ws;
    double* block_comp = dws;                              // NB*7
    double* block_excl = block_comp + NB * 7;              // NB*7
    double* wave_excl  = block_excl + NB * 7;              // NB*NWAVES*7
    double* accum      = wave_excl + NB * NWAVES * 7;      // 2
    unsigned int* counter = (unsigned int*)(accum + 2);

    k_upsweep<<<NB, NT, 0, stream>>>(t, band, y, yerr, lad, lkp,
                                     block_comp, wave_excl);
    k_spine<<<1, NT, 0, stream>>>(block_comp, block_excl, accum, counter);
    k_replay<<<NB, NT, 0, stream>>>(t, band, y, yerr, lad, lkp,
                                    block_excl, wave_excl, accum, counter,
                                    (float*)d_out);
}